// Round 9
// baseline (493.258 us; speedup 1.0000x reference)
//
#include <hip/hip_runtime.h>
#include <math.h>

#define NN 10000
#define EE 320000
#define KK 100
#define PSTR 625   // LSE stripes
#define RSTR 16    // rows per stripe (PSTR*RSTR == NN)

// ---------------- big fp32 GEMM: 64x64x32, register double-buffered staging ----------------
#define BM 64
#define BN 64
#define BK 32

__global__ __launch_bounds__(256) void k_gemm(
    const float* __restrict__ A, const float* __restrict__ B,
    const float* __restrict__ bias, float* __restrict__ C,
    int M, int K, int N, int relu)
{
    __shared__ float As[BK][BM + 4];
    __shared__ float Bs[BK][BN + 4];
    const int tid = threadIdx.x;
    const int bm = blockIdx.y * BM;
    const int bn = blockIdx.x * BN;
    const int tx = tid & 15, ty = tid >> 4;
    float acc[4][4] = {};
    const int ar = tid >> 3;          // 0..31
    const int ac = (tid & 7) << 2;    // 0..28
    const int br = tid >> 4;          // 0..15
    const int bc = (tid & 15) << 2;   // 0..60

    float4 ra[2], rb[2];
    #pragma unroll
    for (int p = 0; p < 2; ++p) {
        int gm = bm + ar + p * 32;
        ra[p] = make_float4(0.f, 0.f, 0.f, 0.f);
        if (gm < M) ra[p] = *(const float4*)(A + (size_t)gm * K + ac);
        int gn = bn + bc;
        rb[p] = make_float4(0.f, 0.f, 0.f, 0.f);
        if (gn < N) rb[p] = *(const float4*)(B + (size_t)(br + p * 16) * N + gn);
    }

    for (int k0 = 0; k0 < K; k0 += BK) {
        #pragma unroll
        for (int p = 0; p < 2; ++p) {
            int r = ar + p * 32;
            As[ac + 0][r] = ra[p].x;
            As[ac + 1][r] = ra[p].y;
            As[ac + 2][r] = ra[p].z;
            As[ac + 3][r] = ra[p].w;
            *(float4*)&Bs[br + p * 16][bc] = rb[p];
        }
        __syncthreads();
        int kn = k0 + BK;
        if (kn < K) {
            #pragma unroll
            for (int p = 0; p < 2; ++p) {
                int gm = bm + ar + p * 32;
                ra[p] = make_float4(0.f, 0.f, 0.f, 0.f);
                if (gm < M) ra[p] = *(const float4*)(A + (size_t)gm * K + kn + ac);
                int gn = bn + bc;
                rb[p] = make_float4(0.f, 0.f, 0.f, 0.f);
                if (gn < N) rb[p] = *(const float4*)(B + (size_t)(kn + br + p * 16) * N + gn);
            }
        }
        #pragma unroll
        for (int k = 0; k < BK; ++k) {
            float4 a4 = *(const float4*)&As[k][ty << 2];
            float4 b4 = *(const float4*)&Bs[k][tx << 2];
            float av[4] = {a4.x, a4.y, a4.z, a4.w};
            float bv[4] = {b4.x, b4.y, b4.z, b4.w};
            #pragma unroll
            for (int i = 0; i < 4; ++i)
                #pragma unroll
                for (int j = 0; j < 4; ++j)
                    acc[i][j] = fmaf(av[i], bv[j], acc[i][j]);
        }
        __syncthreads();
    }
    #pragma unroll
    for (int i = 0; i < 4; ++i) {
        int gm = bm + (ty << 2) + i;
        if (gm >= M) continue;
        #pragma unroll
        for (int j = 0; j < 4; ++j) {
            int gn = bn + (tx << 2) + j;
            if (gn >= N) continue;
            float v = acc[i][j];
            if (bias) v += bias[gn];
            if (relu) v = fmaxf(v, 0.f);
            C[(size_t)gm * N + gn] = v;
        }
    }
}

// ---------------- wide fp32 GEMM: 64x128x32, 4x8 micro-tile (N%128==0) ----------------
__global__ __launch_bounds__(256) void k_gemm3(
    const float* __restrict__ A, const float* __restrict__ B,
    const float* __restrict__ bias, float* __restrict__ C,
    int M, int K, int N, int relu)
{
    __shared__ float As[BK][BM + 4];        // 32 x 68
    __shared__ float Bs[BK][128 + 4];       // 32 x 132
    const int tid = threadIdx.x;
    const int bm = blockIdx.y * BM;
    const int bn = blockIdx.x * 128;
    const int tx = tid & 15, ty = tid >> 4;
    float acc[2][4][4] = {};
    // A staging: 64x32 = 512 float4, 2/thread
    const int ar = tid >> 3;                // 0..31
    const int ac = (tid & 7) << 2;          // 0..28
    // B staging: 32x128 = 1024 float4, 4/thread
    const int br = tid >> 5;                // 0..7
    const int bc = (tid & 31) << 2;         // 0..124

    float4 ra[2], rb[4];
    #pragma unroll
    for (int p = 0; p < 2; ++p) {
        int gm = bm + ar + p * 32;
        ra[p] = make_float4(0.f, 0.f, 0.f, 0.f);
        if (gm < M) ra[p] = *(const float4*)(A + (size_t)gm * K + ac);
    }
    #pragma unroll
    for (int p = 0; p < 4; ++p)
        rb[p] = *(const float4*)(B + (size_t)(br + p * 8) * N + bn + bc);

    for (int k0 = 0; k0 < K; k0 += BK) {
        #pragma unroll
        for (int p = 0; p < 2; ++p) {
            int r = ar + p * 32;
            As[ac + 0][r] = ra[p].x;
            As[ac + 1][r] = ra[p].y;
            As[ac + 2][r] = ra[p].z;
            As[ac + 3][r] = ra[p].w;
        }
        #pragma unroll
        for (int p = 0; p < 4; ++p)
            *(float4*)&Bs[br + p * 8][bc] = rb[p];
        __syncthreads();
        int kn = k0 + BK;
        if (kn < K) {
            #pragma unroll
            for (int p = 0; p < 2; ++p) {
                int gm = bm + ar + p * 32;
                ra[p] = make_float4(0.f, 0.f, 0.f, 0.f);
                if (gm < M) ra[p] = *(const float4*)(A + (size_t)gm * K + kn + ac);
            }
            #pragma unroll
            for (int p = 0; p < 4; ++p)
                rb[p] = *(const float4*)(B + (size_t)(kn + br + p * 8) * N + bn + bc);
        }
        #pragma unroll
        for (int k = 0; k < BK; ++k) {
            float4 a4 = *(const float4*)&As[k][ty << 2];
            float4 b0 = *(const float4*)&Bs[k][tx << 2];
            float4 b1 = *(const float4*)&Bs[k][64 + (tx << 2)];
            float av[4] = {a4.x, a4.y, a4.z, a4.w};
            float bv[2][4] = {{b0.x, b0.y, b0.z, b0.w}, {b1.x, b1.y, b1.z, b1.w}};
            #pragma unroll
            for (int i = 0; i < 4; ++i)
                #pragma unroll
                for (int ch = 0; ch < 2; ++ch)
                    #pragma unroll
                    for (int j = 0; j < 4; ++j)
                        acc[ch][i][j] = fmaf(av[i], bv[ch][j], acc[ch][i][j]);
        }
        __syncthreads();
    }
    #pragma unroll
    for (int i = 0; i < 4; ++i) {
        int gm = bm + (ty << 2) + i;
        if (gm >= M) continue;
        #pragma unroll
        for (int ch = 0; ch < 2; ++ch) {
            int gn = bn + ch * 64 + (tx << 2);
            float4 v = make_float4(acc[ch][i][0], acc[ch][i][1],
                                   acc[ch][i][2], acc[ch][i][3]);
            if (bias) {
                float4 bb = *(const float4*)(bias + gn);
                v.x += bb.x; v.y += bb.y; v.z += bb.z; v.w += bb.w;
            }
            if (relu) {
                v.x = fmaxf(v.x, 0.f); v.y = fmaxf(v.y, 0.f);
                v.z = fmaxf(v.z, 0.f); v.w = fmaxf(v.w, 0.f);
            }
            *(float4*)(C + (size_t)gm * N + gn) = v;
        }
    }
}

// ---------------- degree histogram (int only -> deterministic) ----------------
__global__ __launch_bounds__(256) void k_count(
    const int* __restrict__ ecol, int* __restrict__ counts)
{
    int e = blockIdx.x * 256 + threadIdx.x;
    if (e >= EE) return;
    atomicAdd(&counts[ecol[e]], 1);
}

__global__ __launch_bounds__(256) void k_dinv(
    const float* __restrict__ degsum, float* __restrict__ dinv, float* __restrict__ dinv2)
{
    int i = blockIdx.x * 256 + threadIdx.x;
    if (i >= NN) return;
    float d = 1.0f / sqrtf(degsum[i] + 1.0f);
    dinv[i] = d;
    dinv2[i] = d * d;
}

// ---------------- single-block exclusive scan ----------------
template<int PER>
__global__ void k_scan(const int* __restrict__ cnt, int* __restrict__ ptr, int n)
{
    __shared__ int ps[1024];
    const int T = blockDim.x;
    const int t = threadIdx.x;
    int loc[PER];
    int s = 0;
    #pragma unroll
    for (int u = 0; u < PER; ++u) {
        int i = t * PER + u;
        int v = (i < n) ? cnt[i] : 0;
        loc[u] = s;
        s += v;
    }
    ps[t] = s;
    __syncthreads();
    for (int off = 1; off < T; off <<= 1) {
        int v = (t >= off) ? ps[t - off] : 0;
        __syncthreads();
        ps[t] += v;
        __syncthreads();
    }
    int base = (t > 0) ? ps[t - 1] : 0;
    #pragma unroll
    for (int u = 0; u < PER; ++u) {
        int i = t * PER + u;
        if (i < n) ptr[i] = base + loc[u];
    }
    if (t == T - 1) ptr[n] = ps[T - 1];
}

// ---------------- scatter edges (arbitrary order; canonicalized by sort after) ----------------
__global__ __launch_bounds__(256) void k_scatter_e(
    const int* __restrict__ erow, const int* __restrict__ ecol, const float* __restrict__ ew,
    const int* __restrict__ ptr, int* __restrict__ cursor,
    int* __restrict__ srcs, float* __restrict__ ews, int* __restrict__ colix)
{
    int e = blockIdx.x * 256 + threadIdx.x;
    if (e >= EE) return;
    int r = erow[e], c = ecol[e];
    int pos = ptr[c] + atomicAdd(&cursor[c], 1);
    srcs[pos] = r;
    ews[pos] = ew[e];
    colix[pos] = c;
}

// ---------------- canonical per-column sort (determinism) + deterministic degsum ----------------
__global__ __launch_bounds__(256) void k_sortcol(
    const int* __restrict__ colptr, int* __restrict__ srcs, float* __restrict__ ews,
    float* __restrict__ degsum)
{
    __shared__ unsigned long long keys[4][256];
    __shared__ int mxs;
    int wave = threadIdx.x >> 6, lane = threadIdx.x & 63;
    int v = blockIdx.x * 4 + wave;            // NN divisible by 4
    int beg = colptr[v];
    int cnt = colptr[v + 1] - beg;
    if (cnt > 256) cnt = 256;                 // cannot happen (Poisson(32)); safety
    if (threadIdx.x == 0) mxs = 0;
    __syncthreads();
    if (lane == 0) atomicMax(&mxs, cnt);
    for (int j = lane; j < cnt; j += 64)
        keys[wave][j] = ((unsigned long long)(unsigned)srcs[beg + j] << 32)
                      | (unsigned long long)__float_as_uint(ews[beg + j]);
    __syncthreads();
    int mx = mxs;
    for (int ph = 0; ph < mx; ++ph) {
        int r = ph & 1;
        #pragma unroll
        for (int pp = 0; pp < 2; ++pp) {
            int i = 2 * (lane + pp * 64) + r;
            if (i + 1 < cnt) {
                unsigned long long a = keys[wave][i], b = keys[wave][i + 1];
                if (a > b) { keys[wave][i] = b; keys[wave][i + 1] = a; }
            }
        }
        __syncthreads();
    }
    float s = 0.f;
    for (int j = lane; j < cnt; j += 64)
        s += __uint_as_float((unsigned)(keys[wave][j] & 0xffffffffULL));
    #pragma unroll
    for (int o = 32; o; o >>= 1) s += __shfl_xor(s, o, 64);
    if (lane == 0) degsum[v] = s;
    for (int j = lane; j < cnt; j += 64) {
        unsigned long long k2 = keys[wave][j];
        srcs[beg + j] = (int)(k2 >> 32);
        ews[beg + j] = __uint_as_float((unsigned)(k2 & 0xffffffffULL));
    }
}

// ---------------- per-entry norm (elementwise, deterministic) ----------------
__global__ __launch_bounds__(256) void k_norms(
    const int* __restrict__ srcs, const float* __restrict__ ews, const int* __restrict__ colix,
    const float* __restrict__ dinv, float* __restrict__ norms)
{
    int p = blockIdx.x * 256 + threadIdx.x;
    if (p >= EE) return;
    norms[p] = dinv[srcs[p]] * ews[p] * dinv[colix[p]];
}

// ---------------- sparse aggregation: wave per node, 4 feats/lane ----------------
__global__ __launch_bounds__(256) void k_agg(
    const int* __restrict__ ptr, const int* __restrict__ srcs, const float* __restrict__ norms,
    const float* __restrict__ h, const float* __restrict__ dinv2, const float* __restrict__ bias,
    float* __restrict__ outp, int relu)
{
    int wave = threadIdx.x >> 6;
    int lane = threadIdx.x & 63;
    int v = blockIdx.x * 4 + wave;
    if (v >= NN) return;
    int beg = ptr[v], end = ptr[v + 1];
    float4 acc = make_float4(0.f, 0.f, 0.f, 0.f);
    for (int j = beg; j < end; ++j) {
        int s = srcs[j];
        float nw = norms[j];
        float4 hv = *(const float4*)(h + (size_t)s * 256 + lane * 4);
        acc.x = fmaf(nw, hv.x, acc.x);
        acc.y = fmaf(nw, hv.y, acc.y);
        acc.z = fmaf(nw, hv.z, acc.z);
        acc.w = fmaf(nw, hv.w, acc.w);
    }
    float d2 = dinv2[v];
    float4 hv = *(const float4*)(h + (size_t)v * 256 + lane * 4);
    float4 bv = *(const float4*)(bias + lane * 4);
    acc.x = fmaf(d2, hv.x, acc.x) + bv.x;
    acc.y = fmaf(d2, hv.y, acc.y) + bv.y;
    acc.z = fmaf(d2, hv.z, acc.z) + bv.z;
    acc.w = fmaf(d2, hv.w, acc.w) + bv.w;
    if (relu) {
        acc.x = fmaxf(acc.x, 0.f); acc.y = fmaxf(acc.y, 0.f);
        acc.z = fmaxf(acc.z, 0.f); acc.w = fmaxf(acc.w, 0.f);
    }
    *(float4*)(outp + (size_t)v * 256 + lane * 4) = acc;
}

// ---------------- column LSE pass 1: 625 stripes x 16 rows, deterministic ----------------
__global__ __launch_bounds__(256) void k_colpart(
    const float* __restrict__ z, float* __restrict__ partM, float* __restrict__ partS)
{
    __shared__ float tile[RSTR][KK];
    __shared__ float m1s[128], s1s[128];
    const int p = blockIdx.x;
    const int t = threadIdx.x;
    const float4* zsrc = (const float4*)(z + (size_t)p * RSTR * KK);
    float* tf = &tile[0][0];
    for (int i = t; i < RSTR * KK / 4; i += 256)
        *(float4*)(tf + i * 4) = zsrc[i];
    __syncthreads();
    const int g = t >> 7;
    const int c = t & 127;
    float m = -INFINITY, s = 0.f;
    if (c < KK) {
        const int rb = g * 8;
        #pragma unroll
        for (int r = 0; r < 8; ++r) {
            float v = tile[rb + r][c];
            if (v <= m) {
                s += expf(v - m);
            } else {
                s = s * expf(m - v) + 1.f;
                m = v;
            }
        }
        if (g) { m1s[c] = m; s1s[c] = s; }
    }
    __syncthreads();
    if (c < KK && g == 0) {
        float m2 = m1s[c], s2 = s1s[c];
        float M = fmaxf(m, m2);
        float S = s * expf(m - M) + s2 * expf(m2 - M);
        partM[(size_t)p * KK + c] = M;
        partS[(size_t)p * KK + c] = S;
    }
}

// ---------------- column LSE pass 2: block per column, fixed-shape tree ----------------
__global__ __launch_bounds__(128) void k_colred(
    const float* __restrict__ partM, const float* __restrict__ partS, float* __restrict__ L)
{
    __shared__ float Ms[128], Ss[128];
    const int k = blockIdx.x;
    const int t = threadIdx.x;
    float m = -INFINITY, s = 0.f;
    for (int p = t; p < PSTR; p += 128) {
        float m2 = partM[(size_t)p * KK + k], s2 = partS[(size_t)p * KK + k];
        if (m2 <= m) {
            s += s2 * expf(m2 - m);
        } else {
            s = s * expf(m - m2) + s2;
            m = m2;
        }
    }
    Ms[t] = m; Ss[t] = s;
    __syncthreads();
    for (int off = 64; off; off >>= 1) {
        if (t < off) {
            float m1 = Ms[t], s1 = Ss[t];
            float m2 = Ms[t + off], s2 = Ss[t + off];
            float M = fmaxf(m1, m2);
            Ms[t] = M;
            Ss[t] = s1 * expf(m1 - M) + s2 * expf(m2 - M);
        }
        __syncthreads();
    }
    if (t == 0) L[k] = Ms[0] + logf(Ss[0]);
}

// ---------------- row argmax of (z - L): wave per row; write one-hot map ----------------
__global__ __launch_bounds__(256) void k_argmax(
    const float* __restrict__ z, const float* __restrict__ L, float* __restrict__ mapm,
    int* __restrict__ cass, int* __restrict__ tie, int* __restrict__ colcount)
{
    __shared__ float Ls[KK];
    int t = threadIdx.x;
    if (t < KK) Ls[t] = L[t];
    __syncthreads();
    int lane = t & 63, wave = t >> 6;
    int i = blockIdx.x * 4 + wave;
    if (i >= NN) return;
    const float* zr = z + (size_t)i * KK;
    float v0 = zr[lane] - Ls[lane];
    float v1 = (lane < KK - 64) ? (zr[lane + 64] - Ls[lane + 64]) : -INFINITY;
    float m = fmaxf(v0, v1);
    #pragma unroll
    for (int o = 32; o; o >>= 1) m = fmaxf(m, __shfl_xor(m, o, 64));
    bool p0 = (v0 == m);
    bool p1 = (lane < KK - 64) && (v1 == m);
    unsigned long long b0 = __ballot(p0);
    unsigned long long b1 = __ballot(p1);
    int n = __popcll(b0) + __popcll(b1);
    float* mr = mapm + (size_t)i * KK;
    mr[lane] = p0 ? 1.f : 0.f;
    if (lane < KK - 64) mr[64 + lane] = p1 ? 1.f : 0.f;
    if (p0) atomicAdd(&colcount[lane], 1);
    if (p1) atomicAdd(&colcount[64 + lane], 1);
    if (lane == 0) {
        int k0 = b0 ? (__ffsll((long long)b0) - 1) : (64 + __ffsll((long long)b1) - 1);
        cass[i] = k0;
        tie[i] = (n > 1) ? 1 : 0;
    }
}

// ---------------- scatter rows into per-cluster lists ----------------
__global__ __launch_bounds__(256) void k_scatter_rows(
    const int* __restrict__ cass, const int* __restrict__ tie, const float* __restrict__ mapm,
    const int* __restrict__ clptr, int* __restrict__ clcur, int* __restrict__ rows, int cap)
{
    int i = blockIdx.x * 256 + threadIdx.x;
    if (i >= NN) return;
    if (!tie[i]) {
        int k = cass[i];
        int pos = clptr[k] + atomicAdd(&clcur[k], 1);
        if (pos < cap) rows[pos] = i;
    } else {
        for (int k = 0; k < KK; ++k) {
            if (mapm[(size_t)i * KK + k] == 1.f) {
                int pos = clptr[k] + atomicAdd(&clcur[k], 1);
                if (pos < cap) rows[pos] = i;
            }
        }
    }
}

// ---------------- region = map^T @ hB: wave-split rows, dual accumulators ----------------
__global__ __launch_bounds__(256) void k_region(
    const int* __restrict__ clptr, const int* __restrict__ rows,
    const float* __restrict__ hB, float* __restrict__ region)
{
    __shared__ float4 red[4][64];
    const int k = blockIdx.x;
    const int lane = threadIdx.x & 63, kg = threadIdx.x >> 6;
    const int beg = clptr[k], end = clptr[k + 1];
    float4 a0 = make_float4(0.f, 0.f, 0.f, 0.f);
    float4 a1 = make_float4(0.f, 0.f, 0.f, 0.f);
    int j = beg + kg;
    for (; j + 4 < end; j += 8) {
        const float* p0 = hB + (size_t)rows[j] * 256 + lane * 4;
        const float* p1 = hB + (size_t)rows[j + 4] * 256 + lane * 4;
        float4 v0 = *(const float4*)p0;
        float4 v1 = *(const float4*)p1;
        a0.x += v0.x; a0.y += v0.y; a0.z += v0.z; a0.w += v0.w;
        a1.x += v1.x; a1.y += v1.y; a1.z += v1.z; a1.w += v1.w;
    }
    if (j < end) {
        float4 v0 = *(const float4*)(hB + (size_t)rows[j] * 256 + lane * 4);
        a0.x += v0.x; a0.y += v0.y; a0.z += v0.z; a0.w += v0.w;
    }
    a0.x += a1.x; a0.y += a1.y; a0.z += a1.z; a0.w += a1.w;
    red[kg][lane] = a0;
    __syncthreads();
    if (kg == 0) {
        float4 r = red[0][lane];
        #pragma unroll
        for (int g = 1; g < 4; ++g) {
            float4 q = red[g][lane];
            r.x += q.x; r.y += q.y; r.z += q.z; r.w += q.w;
        }
        *(float4*)(region + (size_t)k * 256 + lane * 4) = r;
    }
}

// ---------------- out_adj = map^T adj map via per-edge atomics ----------------
__global__ __launch_bounds__(256) void k_outadj(
    const int* __restrict__ erow, const int* __restrict__ ecol, const float* __restrict__ ew,
    const int* __restrict__ cass, const int* __restrict__ tie, const float* __restrict__ mapm,
    float* __restrict__ oadj)
{
    int e = blockIdx.x * 256 + threadIdx.x;
    if (e >= EE) return;
    int s = erow[e], d = ecol[e];
    float wv = ew[e];
    if (!tie[s] && !tie[d]) {
        atomicAdd(&oadj[cass[s] * KK + cass[d]], wv);
    } else {
        for (int ks = 0; ks < KK; ++ks) {
            if (mapm[(size_t)s * KK + ks] != 1.f) continue;
            for (int kd = 0; kd < KK; ++kd) {
                if (mapm[(size_t)d * KK + kd] != 1.f) continue;
                atomicAdd(&oadj[ks * KK + kd], wv);
            }
        }
    }
}

// ---------------- zero diag, colsums -> dinv_r, losses ----------------
__global__ __launch_bounds__(128) void k_finalize(
    float* __restrict__ oadj, const int* __restrict__ colcount,
    float* __restrict__ dinvr, float* __restrict__ lossout)
{
    int t = threadIdx.x;
    if (t < KK) oadj[t * KK + t] = 0.f;
    __syncthreads();
    if (t < KK) {
        float s = 1.f;   // +I on the diagonal
        for (int i = 0; i < KK; ++i) s += oadj[i * KK + t];
        dinvr[t] = 1.0f / sqrtf(s);
    }
    if (t == 0) {
        float s = 0.f;
        long long tot = 0;
        for (int k = 0; k < KK; ++k) {
            s += sqrtf((float)colcount[k] + 1e-15f);
            tot += colcount[k];
        }
        lossout[0] = -s / 1000.0f;                                  // sqrt(N*K)=1000
        lossout[1] = (float)tot * (-logf(1.0f + 1e-6f)) / 10000.0f;
    }
}

// ---------------- small GEMM: latency-optimized (tiny M, K<=512) ----------------
__global__ __launch_bounds__(256) void k_sgemm(
    const float* __restrict__ A, const float* __restrict__ B, const float* __restrict__ bias,
    float* __restrict__ C, int K, int N, int relu)
{
    __shared__ float a_s[512];
    __shared__ float4 red[4][64];
    const int tid = threadIdx.x;
    const int lane = tid & 63, kg = tid >> 6;
    const int m = blockIdx.y;
    const int n0 = blockIdx.x * 256 + lane * 4;
    for (int k = tid; k < K; k += 256) a_s[k] = A[(size_t)m * K + k];
    __syncthreads();
    float4 acc = make_float4(0.f, 0.f, 0.f, 0.f);
    const int kq = K >> 2;
    const int kb = kg * kq, ke = kb + kq;
    if (n0 < N) {
        #pragma unroll 4
        for (int k = kb; k < ke; ++k) {
            float av = a_s[k];
            float4 b4 = *(const float4*)(B + (size_t)k * N + n0);
            acc.x = fmaf(av, b4.x, acc.x);
            acc.y = fmaf(av, b4.y, acc.y);
            acc.z = fmaf(av, b4.z, acc.z);
            acc.w = fmaf(av, b4.w, acc.w);
        }
    }
    red[kg][lane] = acc;
    __syncthreads();
    if (kg == 0 && n0 < N) {
        float4 r = red[0][lane];
        #pragma unroll
        for (int g = 1; g < 4; ++g) {
            float4 q = red[g][lane];
            r.x += q.x; r.y += q.y; r.z += q.z; r.w += q.w;
        }
        if (bias) {
            float4 bv = *(const float4*)(bias + n0);
            r.x += bv.x; r.y += bv.y; r.z += bv.z; r.w += bv.w;
        }
        if (relu) {
            r.x = fmaxf(r.x, 0.f); r.y = fmaxf(r.y, 0.f);
            r.z = fmaxf(r.z, 0.f); r.w = fmaxf(r.w, 0.f);
        }
        *(float4*)(C + (size_t)m * N + n0) = r;
    }
}

// ---------------- pooled-graph propagation: LDS-staged weights, j-split ----------------
__global__ __launch_bounds__(256) void k_pool(
    const float* __restrict__ oadj, const float* __restrict__ dinv, const float* __restrict__ h,
    const float* __restrict__ bias, float* __restrict__ outp, int F, int relu)
{
    __shared__ float wjs[KK];
    __shared__ float4 red[4][64];
    const int tid = threadIdx.x;
    const int lane = tid & 63, kg = tid >> 6;
    const int i = blockIdx.y;
    if (tid < KK)
        wjs[tid] = (oadj[tid * KK + i] + ((tid == i) ? 1.f : 0.f)) * dinv[tid];
    __syncthreads();
    const int f0 = blockIdx.x * 256 + lane * 4;
    float4 acc = make_float4(0.f, 0.f, 0.f, 0.f);
    if (f0 < F) {
        #pragma unroll 5
        for (int j = kg * 25; j < kg * 25 + 25; ++j) {
            float wv = wjs[j];
            float4 h4 = *(const float4*)(h + (size_t)j * F + f0);
            acc.x = fmaf(wv, h4.x, acc.x);
            acc.y = fmaf(wv, h4.y, acc.y);
            acc.z = fmaf(wv, h4.z, acc.z);
            acc.w = fmaf(wv, h4.w, acc.w);
        }
    }
    red[kg][lane] = acc;
    __syncthreads();
    if (kg == 0 && f0 < F) {
        float4 r = red[0][lane];
        #pragma unroll
        for (int g = 1; g < 4; ++g) {
            float4 q = red[g][lane];
            r.x += q.x; r.y += q.y; r.z += q.z; r.w += q.w;
        }
        float di = dinv[i];
        float4 bv = *(const float4*)(bias + f0);
        r.x = di * r.x + bv.x; r.y = di * r.y + bv.y;
        r.z = di * r.z + bv.z; r.w = di * r.w + bv.w;
        if (relu) {
            r.x = fmaxf(r.x, 0.f); r.y = fmaxf(r.y, 0.f);
            r.z = fmaxf(r.z, 0.f); r.w = fmaxf(r.w, 0.f);
        }
        *(float4*)(outp + (size_t)i * F + f0) = r;
    }
}

// ---------------- final dot ----------------
__global__ __launch_bounds__(256) void k_rowdot(
    const float* __restrict__ A, const float* __restrict__ wv, const float* __restrict__ b,
    float* __restrict__ outp, int K)
{
    __shared__ float red[256];
    int m = blockIdx.x, t = threadIdx.x;
    float acc = 0.f;
    for (int k = t; k < K; k += 256)
        acc = fmaf(A[(size_t)m * K + k], wv[k], acc);
    red[t] = acc;
    __syncthreads();
    for (int off = 128; off; off >>= 1) {
        if (t < off) red[t] += red[t + off];
        __syncthreads();
    }
    if (t == 0) outp[m] = red[0] + b[0];
}

extern "C" void kernel_launch(void* const* d_in, const int* in_sizes, int n_in,
                              void* d_out, int out_size, void* d_ws, size_t ws_size,
                              hipStream_t stream)
{
    const float* x   = (const float*)d_in[0];
    const int*   ei  = (const int*)  d_in[1];
    const float* ew  = (const float*)d_in[2];
    const float* w1  = (const float*)d_in[3];
    const float* b1  = (const float*)d_in[4];
    const float* w2  = (const float*)d_in[5];
    const float* b2  = (const float*)d_in[6];
    const float* aw1 = (const float*)d_in[7];
    const float* ab1 = (const float*)d_in[8];
    const float* aw2 = (const float*)d_in[9];
    const float* ab2 = (const float*)d_in[10];
    const float* w3  = (const float*)d_in[11];
    const float* b3  = (const float*)d_in[12];
    const float* w4  = (const float*)d_in[13];
    const float* b4  = (const float*)d_in[14];
    const float* pw1 = (const float*)d_in[15];
    const float* pb1 = (const float*)d_in[16];
    const float* pw2 = (const float*)d_in[17];
    const float* pb2 = (const float*)d_in[18];
    const float* pw3 = (const float*)d_in[19];
    const float* pb3 = (const float*)d_in[20];

    const int* erow = ei;
    const int* ecol = ei + EE;
    float* out = (float*)d_out;

    char* w = (char*)d_ws;
    size_t off = 0;
    auto alloc = [&](size_t bytes) -> void* {
        void* p = w + off;
        off = (off + bytes + 255) & ~(size_t)255;
        return p;
    };

    // -------- zeroed-per-call region (single memset) --------
    size_t zbeg = off;
    int*   counts   = (int*)  alloc(NN * 4);
    int*   cursor   = (int*)  alloc(NN * 4);
    int*   colcount = (int*)  alloc(KK * 4);
    int*   clcur    = (int*)  alloc(KK * 4);
    float* oadj     = (float*)alloc(KK * KK * 4);
    size_t zend = off;

    float* degsum = (float*)alloc(NN * 4);
    float* dinv   = (float*)alloc(NN * 4);
    float* dinv2  = (float*)alloc(NN * 4);
    int*   colptr = (int*)  alloc((NN + 1) * 4);
    int*   srcs   = (int*)  alloc((size_t)EE * 4);
    float* ews    = (float*)alloc((size_t)EE * 4);
    int*   colix  = (int*)  alloc((size_t)EE * 4);
    float* norms  = (float*)alloc((size_t)EE * 4);
    float* partM  = (float*)alloc((size_t)PSTR * KK * 4);
    float* partS  = (float*)alloc((size_t)PSTR * KK * 4);
    float* Lc     = (float*)alloc(KK * 4);
    int*   cass   = (int*)  alloc(NN * 4);
    int*   tie    = (int*)  alloc(NN * 4);
    int*   clptr  = (int*)  alloc((KK + 1) * 4);
    const int rowcap = NN + 2048;
    int*   rowss  = (int*)  alloc((size_t)rowcap * 4);
    float* region = (float*)alloc((size_t)KK * 256 * 4);
    float* dinvr  = (float*)alloc(KK * 4);
    float* hs1    = (float*)alloc((size_t)KK * 512 * 4);
    float* xr1    = (float*)alloc((size_t)KK * 512 * 4);
    float* hs2    = (float*)alloc((size_t)KK * 256 * 4);
    float* p1     = (float*)alloc((size_t)KK * 512 * 4);
    float* p2     = (float*)alloc((size_t)KK * 512 * 4);
    float* bufA   = (float*)alloc((size_t)NN * 256 * 4);
    float* bufB   = (float*)alloc((size_t)NN * 256 * 4);
    float* abuf   = (float*)alloc((size_t)NN * 512 * 4);
    float* zbuf   = (float*)alloc((size_t)NN * KK * 4);

    hipMemsetAsync(w + zbeg, 0, zend - zbeg, stream);

    // graph preprocessing: CSC by target, canonical (sorted) order, deterministic degsum
    k_count<<<(EE + 255) / 256, 256, 0, stream>>>(ecol, counts);
    k_scan<10><<<1, 1024, 0, stream>>>(counts, colptr, NN);
    k_scatter_e<<<(EE + 255) / 256, 256, 0, stream>>>(erow, ecol, ew, colptr, cursor,
                                                      srcs, ews, colix);
    k_sortcol<<<NN / 4, 256, 0, stream>>>(colptr, srcs, ews, degsum);
    k_dinv<<<(NN + 255) / 256, 256, 0, stream>>>(degsum, dinv, dinv2);
    k_norms<<<(EE + 255) / 256, 256, 0, stream>>>(srcs, ews, colix, dinv, norms);

    // GCN layer 1: h1 = x@w1 ; agg + self + b1 ; relu
    k_gemm<<<dim3(4, 157), 256, 0, stream>>>(x, w1, nullptr, bufA, NN, 128, 256, 0);
    k_agg<<<NN / 4, 256, 0, stream>>>(colptr, srcs, norms, bufA, dinv2, b1, bufB, 1);
    // GCN layer 2
    k_gemm<<<dim3(4, 157), 256, 0, stream>>>(bufB, w2, nullptr, bufA, NN, 256, 256, 0);
    k_agg<<<NN / 4, 256, 0, stream>>>(colptr, srcs, norms, bufA, dinv2, b2, bufB, 0);

    // assignment MLP (aw1 GEMM on the wide-tile kernel: N=512 % 128 == 0)
    k_gemm3<<<dim3(4, 157), 256, 0, stream>>>(bufB, aw1, ab1, abuf, NN, 256, 512, 1);
    k_gemm<<<dim3(2, 157), 256, 0, stream>>>(abuf, aw2, ab2, zbuf, NN, 512, 100, 0);

    // softmax(axis=0) -> row argmax -> one-hot map (written straight to d_out)
    k_colpart<<<PSTR, 256, 0, stream>>>(zbuf, partM, partS);
    k_colred<<<KK, 128, 0, stream>>>(partM, partS, Lc);
    k_argmax<<<NN / 4, 256, 0, stream>>>(zbuf, Lc, out, cass, tie, colcount);

    // pooling
    k_scan<1><<<1, 128, 0, stream>>>(colcount, clptr, KK);
    k_scatter_rows<<<(NN + 255) / 256, 256, 0, stream>>>(cass, tie, out, clptr, clcur,
                                                         rowss, rowcap);
    k_region<<<KK, 256, 0, stream>>>(clptr, rowss, bufB, region);
    k_outadj<<<(EE + 255) / 256, 256, 0, stream>>>(erow, ecol, ew, cass, tie, out, oadj);
    k_finalize<<<1, 128, 0, stream>>>(oadj, colcount, dinvr, out + 1000000);

    // dense GCN 1
    k_sgemm<<<dim3(2, KK), 256, 0, stream>>>(region, w3, nullptr, hs1, 256, 512, 0);
    k_pool <<<dim3(2, KK), 256, 0, stream>>>(oadj, dinvr, hs1, b3, xr1, 512, 1);
    // dense GCN 2 -> xr (output)
    k_sgemm<<<dim3(1, KK), 256, 0, stream>>>(xr1, w4, nullptr, hs2, 512, 256, 0);
    k_pool <<<dim3(1, KK), 256, 0, stream>>>(oadj, dinvr, hs2, b4, out + 1000002, 256, 0);

    // MLP readout
    k_sgemm<<<dim3(2, KK), 256, 0, stream>>>(out + 1000002, pw1, pb1, p1, 256, 512, 1);
    k_sgemm<<<dim3(2, KK), 256, 0, stream>>>(p1, pw2, pb2, p2, 512, 512, 1);
    k_rowdot<<<KK, 256, 0, stream>>>(p2, pw3, pb3, out + 1000002 + 25600, 512);
}

// Round 13
// 486.884 us; speedup vs baseline: 1.0131x; 1.0131x over previous
//
#include <hip/hip_runtime.h>
#include <math.h>

#define NN 10000
#define EE 320000
#define KK 100
#define PSTR 625   // LSE stripes
#define RSTR 16    // rows per stripe (PSTR*RSTR == NN)

// ---------------- big fp32 GEMM: 64x64x32, register double-buffered staging ----------------
#define BM 64
#define BN 64
#define BK 32

__global__ __launch_bounds__(256) void k_gemm(
    const float* __restrict__ A, const float* __restrict__ B,
    const float* __restrict__ bias, float* __restrict__ C,
    int M, int K, int N, int relu)
{
    __shared__ float As[BK][BM + 4];
    __shared__ float Bs[BK][BN + 4];
    const int tid = threadIdx.x;
    const int bm = blockIdx.y * BM;
    const int bn = blockIdx.x * BN;
    const int tx = tid & 15, ty = tid >> 4;
    float acc[4][4] = {};
    const int ar = tid >> 3;          // 0..31
    const int ac = (tid & 7) << 2;    // 0..28
    const int br = tid >> 4;          // 0..15
    const int bc = (tid & 15) << 2;   // 0..60

    float4 ra[2], rb[2];
    #pragma unroll
    for (int p = 0; p < 2; ++p) {
        int gm = bm + ar + p * 32;
        ra[p] = make_float4(0.f, 0.f, 0.f, 0.f);
        if (gm < M) ra[p] = *(const float4*)(A + (size_t)gm * K + ac);
        int gn = bn + bc;
        rb[p] = make_float4(0.f, 0.f, 0.f, 0.f);
        if (gn < N) rb[p] = *(const float4*)(B + (size_t)(br + p * 16) * N + gn);
    }

    for (int k0 = 0; k0 < K; k0 += BK) {
        #pragma unroll
        for (int p = 0; p < 2; ++p) {
            int r = ar + p * 32;
            As[ac + 0][r] = ra[p].x;
            As[ac + 1][r] = ra[p].y;
            As[ac + 2][r] = ra[p].z;
            As[ac + 3][r] = ra[p].w;
            *(float4*)&Bs[br + p * 16][bc] = rb[p];
        }
        __syncthreads();
        int kn = k0 + BK;
        if (kn < K) {
            #pragma unroll
            for (int p = 0; p < 2; ++p) {
                int gm = bm + ar + p * 32;
                ra[p] = make_float4(0.f, 0.f, 0.f, 0.f);
                if (gm < M) ra[p] = *(const float4*)(A + (size_t)gm * K + kn + ac);
                int gn = bn + bc;
                rb[p] = make_float4(0.f, 0.f, 0.f, 0.f);
                if (gn < N) rb[p] = *(const float4*)(B + (size_t)(kn + br + p * 16) * N + gn);
            }
        }
        #pragma unroll
        for (int k = 0; k < BK; ++k) {
            float4 a4 = *(const float4*)&As[k][ty << 2];
            float4 b4 = *(const float4*)&Bs[k][tx << 2];
            float av[4] = {a4.x, a4.y, a4.z, a4.w};
            float bv[4] = {b4.x, b4.y, b4.z, b4.w};
            #pragma unroll
            for (int i = 0; i < 4; ++i)
                #pragma unroll
                for (int j = 0; j < 4; ++j)
                    acc[i][j] = fmaf(av[i], bv[j], acc[i][j]);
        }
        __syncthreads();
    }
    #pragma unroll
    for (int i = 0; i < 4; ++i) {
        int gm = bm + (ty << 2) + i;
        if (gm >= M) continue;
        #pragma unroll
        for (int j = 0; j < 4; ++j) {
            int gn = bn + (tx << 2) + j;
            if (gn >= N) continue;
            float v = acc[i][j];
            if (bias) v += bias[gn];
            if (relu) v = fmaxf(v, 0.f);
            C[(size_t)gm * N + gn] = v;
        }
    }
}

// ---------------- degree histogram (int only -> deterministic) ----------------
__global__ __launch_bounds__(256) void k_count(
    const int* __restrict__ ecol, int* __restrict__ counts)
{
    int e = blockIdx.x * 256 + threadIdx.x;
    if (e >= EE) return;
    atomicAdd(&counts[ecol[e]], 1);
}

__global__ __launch_bounds__(256) void k_dinv(
    const float* __restrict__ degsum, float* __restrict__ dinv, float* __restrict__ dinv2)
{
    int i = blockIdx.x * 256 + threadIdx.x;
    if (i >= NN) return;
    float d = 1.0f / sqrtf(degsum[i] + 1.0f);
    dinv[i] = d;
    dinv2[i] = d * d;
}

// ---------------- single-block exclusive scan ----------------
template<int PER>
__global__ void k_scan(const int* __restrict__ cnt, int* __restrict__ ptr, int n)
{
    __shared__ int ps[1024];
    const int T = blockDim.x;
    const int t = threadIdx.x;
    int loc[PER];
    int s = 0;
    #pragma unroll
    for (int u = 0; u < PER; ++u) {
        int i = t * PER + u;
        int v = (i < n) ? cnt[i] : 0;
        loc[u] = s;
        s += v;
    }
    ps[t] = s;
    __syncthreads();
    for (int off = 1; off < T; off <<= 1) {
        int v = (t >= off) ? ps[t - off] : 0;
        __syncthreads();
        ps[t] += v;
        __syncthreads();
    }
    int base = (t > 0) ? ps[t - 1] : 0;
    #pragma unroll
    for (int u = 0; u < PER; ++u) {
        int i = t * PER + u;
        if (i < n) ptr[i] = base + loc[u];
    }
    if (t == T - 1) ptr[n] = ps[T - 1];
}

// ---------------- scatter edges (arbitrary order; canonicalized by sort after) ----------------
__global__ __launch_bounds__(256) void k_scatter_e(
    const int* __restrict__ erow, const int* __restrict__ ecol, const float* __restrict__ ew,
    const int* __restrict__ ptr, int* __restrict__ cursor,
    int* __restrict__ srcs, float* __restrict__ ews, int* __restrict__ colix)
{
    int e = blockIdx.x * 256 + threadIdx.x;
    if (e >= EE) return;
    int r = erow[e], c = ecol[e];
    int pos = ptr[c] + atomicAdd(&cursor[c], 1);
    srcs[pos] = r;
    ews[pos] = ew[e];
    colix[pos] = c;
}

// ---------------- canonical per-column sort (determinism) + deterministic degsum ----------------
__global__ __launch_bounds__(256) void k_sortcol(
    const int* __restrict__ colptr, int* __restrict__ srcs, float* __restrict__ ews,
    float* __restrict__ degsum)
{
    __shared__ unsigned long long keys[4][256];
    __shared__ int mxs;
    int wave = threadIdx.x >> 6, lane = threadIdx.x & 63;
    int v = blockIdx.x * 4 + wave;            // NN divisible by 4
    int beg = colptr[v];
    int cnt = colptr[v + 1] - beg;
    if (cnt > 256) cnt = 256;                 // cannot happen (Poisson(32)); safety
    if (threadIdx.x == 0) mxs = 0;
    __syncthreads();
    if (lane == 0) atomicMax(&mxs, cnt);
    for (int j = lane; j < cnt; j += 64)
        keys[wave][j] = ((unsigned long long)(unsigned)srcs[beg + j] << 32)
                      | (unsigned long long)__float_as_uint(ews[beg + j]);
    __syncthreads();
    int mx = mxs;
    for (int ph = 0; ph < mx; ++ph) {
        int r = ph & 1;
        #pragma unroll
        for (int pp = 0; pp < 2; ++pp) {
            int i = 2 * (lane + pp * 64) + r;
            if (i + 1 < cnt) {
                unsigned long long a = keys[wave][i], b = keys[wave][i + 1];
                if (a > b) { keys[wave][i] = b; keys[wave][i + 1] = a; }
            }
        }
        __syncthreads();
    }
    float s = 0.f;
    for (int j = lane; j < cnt; j += 64)
        s += __uint_as_float((unsigned)(keys[wave][j] & 0xffffffffULL));
    #pragma unroll
    for (int o = 32; o; o >>= 1) s += __shfl_xor(s, o, 64);
    if (lane == 0) degsum[v] = s;
    for (int j = lane; j < cnt; j += 64) {
        unsigned long long k2 = keys[wave][j];
        srcs[beg + j] = (int)(k2 >> 32);
        ews[beg + j] = __uint_as_float((unsigned)(k2 & 0xffffffffULL));
    }
}

// ---------------- per-entry norm (elementwise, deterministic) ----------------
__global__ __launch_bounds__(256) void k_norms(
    const int* __restrict__ srcs, const float* __restrict__ ews, const int* __restrict__ colix,
    const float* __restrict__ dinv, float* __restrict__ norms)
{
    int p = blockIdx.x * 256 + threadIdx.x;
    if (p >= EE) return;
    norms[p] = dinv[srcs[p]] * ews[p] * dinv[colix[p]];
}

// ---------------- sparse aggregation: wave per node, 4 feats/lane ----------------
__global__ __launch_bounds__(256) void k_agg(
    const int* __restrict__ ptr, const int* __restrict__ srcs, const float* __restrict__ norms,
    const float* __restrict__ h, const float* __restrict__ dinv2, const float* __restrict__ bias,
    float* __restrict__ outp, int relu)
{
    int wave = threadIdx.x >> 6;
    int lane = threadIdx.x & 63;
    int v = blockIdx.x * 4 + wave;
    if (v >= NN) return;
    int beg = ptr[v], end = ptr[v + 1];
    float4 acc = make_float4(0.f, 0.f, 0.f, 0.f);
    for (int j = beg; j < end; ++j) {
        int s = srcs[j];
        float nw = norms[j];
        float4 hv = *(const float4*)(h + (size_t)s * 256 + lane * 4);
        acc.x = fmaf(nw, hv.x, acc.x);
        acc.y = fmaf(nw, hv.y, acc.y);
        acc.z = fmaf(nw, hv.z, acc.z);
        acc.w = fmaf(nw, hv.w, acc.w);
    }
    float d2 = dinv2[v];
    float4 hv = *(const float4*)(h + (size_t)v * 256 + lane * 4);
    float4 bv = *(const float4*)(bias + lane * 4);
    acc.x = fmaf(d2, hv.x, acc.x) + bv.x;
    acc.y = fmaf(d2, hv.y, acc.y) + bv.y;
    acc.z = fmaf(d2, hv.z, acc.z) + bv.z;
    acc.w = fmaf(d2, hv.w, acc.w) + bv.w;
    if (relu) {
        acc.x = fmaxf(acc.x, 0.f); acc.y = fmaxf(acc.y, 0.f);
        acc.z = fmaxf(acc.z, 0.f); acc.w = fmaxf(acc.w, 0.f);
    }
    *(float4*)(outp + (size_t)v * 256 + lane * 4) = acc;
}

// ---------------- column LSE pass 1: 625 stripes x 16 rows, deterministic ----------------
__global__ __launch_bounds__(256) void k_colpart(
    const float* __restrict__ z, float* __restrict__ partM, float* __restrict__ partS)
{
    __shared__ float tile[RSTR][KK];
    __shared__ float m1s[128], s1s[128];
    const int p = blockIdx.x;
    const int t = threadIdx.x;
    const float4* zsrc = (const float4*)(z + (size_t)p * RSTR * KK);
    float* tf = &tile[0][0];
    for (int i = t; i < RSTR * KK / 4; i += 256)
        *(float4*)(tf + i * 4) = zsrc[i];
    __syncthreads();
    const int g = t >> 7;
    const int c = t & 127;
    float m = -INFINITY, s = 0.f;
    if (c < KK) {
        const int rb = g * 8;
        #pragma unroll
        for (int r = 0; r < 8; ++r) {
            float v = tile[rb + r][c];
            if (v <= m) {
                s += expf(v - m);
            } else {
                s = s * expf(m - v) + 1.f;
                m = v;
            }
        }
        if (g) { m1s[c] = m; s1s[c] = s; }
    }
    __syncthreads();
    if (c < KK && g == 0) {
        float m2 = m1s[c], s2 = s1s[c];
        float M = fmaxf(m, m2);
        float S = s * expf(m - M) + s2 * expf(m2 - M);
        partM[(size_t)p * KK + c] = M;
        partS[(size_t)p * KK + c] = S;
    }
}

// ---------------- column LSE pass 2: block per column, fixed-shape tree ----------------
__global__ __launch_bounds__(128) void k_colred(
    const float* __restrict__ partM, const float* __restrict__ partS, float* __restrict__ L)
{
    __shared__ float Ms[128], Ss[128];
    const int k = blockIdx.x;
    const int t = threadIdx.x;
    float m = -INFINITY, s = 0.f;
    for (int p = t; p < PSTR; p += 128) {
        float m2 = partM[(size_t)p * KK + k], s2 = partS[(size_t)p * KK + k];
        if (m2 <= m) {
            s += s2 * expf(m2 - m);
        } else {
            s = s * expf(m - m2) + s2;
            m = m2;
        }
    }
    Ms[t] = m; Ss[t] = s;
    __syncthreads();
    for (int off = 64; off; off >>= 1) {
        if (t < off) {
            float m1 = Ms[t], s1 = Ss[t];
            float m2 = Ms[t + off], s2 = Ss[t + off];
            float M = fmaxf(m1, m2);
            Ms[t] = M;
            Ss[t] = s1 * expf(m1 - M) + s2 * expf(m2 - M);
        }
        __syncthreads();
    }
    if (t == 0) L[k] = Ms[0] + logf(Ss[0]);
}

// ---------------- row argmax of (z - L): wave per row; write one-hot map ----------------
__global__ __launch_bounds__(256) void k_argmax(
    const float* __restrict__ z, const float* __restrict__ L, float* __restrict__ mapm,
    int* __restrict__ cass, int* __restrict__ tie, int* __restrict__ colcount)
{
    __shared__ float Ls[KK];
    int t = threadIdx.x;
    if (t < KK) Ls[t] = L[t];
    __syncthreads();
    int lane = t & 63, wave = t >> 6;
    int i = blockIdx.x * 4 + wave;
    if (i >= NN) return;
    const float* zr = z + (size_t)i * KK;
    float v0 = zr[lane] - Ls[lane];
    float v1 = (lane < KK - 64) ? (zr[lane + 64] - Ls[lane + 64]) : -INFINITY;
    float m = fmaxf(v0, v1);
    #pragma unroll
    for (int o = 32; o; o >>= 1) m = fmaxf(m, __shfl_xor(m, o, 64));
    bool p0 = (v0 == m);
    bool p1 = (lane < KK - 64) && (v1 == m);
    unsigned long long b0 = __ballot(p0);
    unsigned long long b1 = __ballot(p1);
    int n = __popcll(b0) + __popcll(b1);
    float* mr = mapm + (size_t)i * KK;
    mr[lane] = p0 ? 1.f : 0.f;
    if (lane < KK - 64) mr[64 + lane] = p1 ? 1.f : 0.f;
    if (p0) atomicAdd(&colcount[lane], 1);
    if (p1) atomicAdd(&colcount[64 + lane], 1);
    if (lane == 0) {
        int k0 = b0 ? (__ffsll((long long)b0) - 1) : (64 + __ffsll((long long)b1) - 1);
        cass[i] = k0;
        tie[i] = (n > 1) ? 1 : 0;
    }
}

// ---------------- scatter rows into per-cluster lists ----------------
__global__ __launch_bounds__(256) void k_scatter_rows(
    const int* __restrict__ cass, const int* __restrict__ tie, const float* __restrict__ mapm,
    const int* __restrict__ clptr, int* __restrict__ clcur, int* __restrict__ rows, int cap)
{
    int i = blockIdx.x * 256 + threadIdx.x;
    if (i >= NN) return;
    if (!tie[i]) {
        int k = cass[i];
        int pos = clptr[k] + atomicAdd(&clcur[k], 1);
        if (pos < cap) rows[pos] = i;
    } else {
        for (int k = 0; k < KK; ++k) {
            if (mapm[(size_t)i * KK + k] == 1.f) {
                int pos = clptr[k] + atomicAdd(&clcur[k], 1);
                if (pos < cap) rows[pos] = i;
            }
        }
    }
}

// ---------------- region = map^T @ hB: wave-split rows, dual accumulators ----------------
__global__ __launch_bounds__(256) void k_region(
    const int* __restrict__ clptr, const int* __restrict__ rows,
    const float* __restrict__ hB, float* __restrict__ region)
{
    __shared__ float4 red[4][64];
    const int k = blockIdx.x;
    const int lane = threadIdx.x & 63, kg = threadIdx.x >> 6;
    const int beg = clptr[k], end = clptr[k + 1];
    float4 a0 = make_float4(0.f, 0.f, 0.f, 0.f);
    float4 a1 = make_float4(0.f, 0.f, 0.f, 0.f);
    int j = beg + kg;
    for (; j + 4 < end; j += 8) {
        const float* p0 = hB + (size_t)rows[j] * 256 + lane * 4;
        const float* p1 = hB + (size_t)rows[j + 4] * 256 + lane * 4;
        float4 v0 = *(const float4*)p0;
        float4 v1 = *(const float4*)p1;
        a0.x += v0.x; a0.y += v0.y; a0.z += v0.z; a0.w += v0.w;
        a1.x += v1.x; a1.y += v1.y; a1.z += v1.z; a1.w += v1.w;
    }
    if (j < end) {
        float4 v0 = *(const float4*)(hB + (size_t)rows[j] * 256 + lane * 4);
        a0.x += v0.x; a0.y += v0.y; a0.z += v0.z; a0.w += v0.w;
    }
    a0.x += a1.x; a0.y += a1.y; a0.z += a1.z; a0.w += a1.w;
    red[kg][lane] = a0;
    __syncthreads();
    if (kg == 0) {
        float4 r = red[0][lane];
        #pragma unroll
        for (int g = 1; g < 4; ++g) {
            float4 q = red[g][lane];
            r.x += q.x; r.y += q.y; r.z += q.z; r.w += q.w;
        }
        *(float4*)(region + (size_t)k * 256 + lane * 4) = r;
    }
}

// ---------------- out_adj = map^T adj map via per-edge atomics ----------------
__global__ __launch_bounds__(256) void k_outadj(
    const int* __restrict__ erow, const int* __restrict__ ecol, const float* __restrict__ ew,
    const int* __restrict__ cass, const int* __restrict__ tie, const float* __restrict__ mapm,
    float* __restrict__ oadj)
{
    int e = blockIdx.x * 256 + threadIdx.x;
    if (e >= EE) return;
    int s = erow[e], d = ecol[e];
    float wv = ew[e];
    if (!tie[s] && !tie[d]) {
        atomicAdd(&oadj[cass[s] * KK + cass[d]], wv);
    } else {
        for (int ks = 0; ks < KK; ++ks) {
            if (mapm[(size_t)s * KK + ks] != 1.f) continue;
            for (int kd = 0; kd < KK; ++kd) {
                if (mapm[(size_t)d * KK + kd] != 1.f) continue;
                atomicAdd(&oadj[ks * KK + kd], wv);
            }
        }
    }
}

// ---------------- zero diag, colsums -> dinv_r, losses ----------------
__global__ __launch_bounds__(128) void k_finalize(
    float* __restrict__ oadj, const int* __restrict__ colcount,
    float* __restrict__ dinvr, float* __restrict__ lossout)
{
    int t = threadIdx.x;
    if (t < KK) oadj[t * KK + t] = 0.f;
    __syncthreads();
    if (t < KK) {
        float s = 1.f;   // +I on the diagonal
        for (int i = 0; i < KK; ++i) s += oadj[i * KK + t];
        dinvr[t] = 1.0f / sqrtf(s);
    }
    if (t == 0) {
        float s = 0.f;
        long long tot = 0;
        for (int k = 0; k < KK; ++k) {
            s += sqrtf((float)colcount[k] + 1e-15f);
            tot += colcount[k];
        }
        lossout[0] = -s / 1000.0f;                                  // sqrt(N*K)=1000
        lossout[1] = (float)tot * (-logf(1.0f + 1e-6f)) / 10000.0f;
    }
}

// ---------------- small GEMM: latency-optimized (tiny M, K<=512) ----------------
__global__ __launch_bounds__(256) void k_sgemm(
    const float* __restrict__ A, const float* __restrict__ B, const float* __restrict__ bias,
    float* __restrict__ C, int K, int N, int relu)
{
    __shared__ float a_s[512];
    __shared__ float4 red[4][64];
    const int tid = threadIdx.x;
    const int lane = tid & 63, kg = tid >> 6;
    const int m = blockIdx.y;
    const int n0 = blockIdx.x * 256 + lane * 4;
    for (int k = tid; k < K; k += 256) a_s[k] = A[(size_t)m * K + k];
    __syncthreads();
    float4 acc = make_float4(0.f, 0.f, 0.f, 0.f);
    const int kq = K >> 2;
    const int kb = kg * kq, ke = kb + kq;
    if (n0 < N) {
        #pragma unroll 4
        for (int k = kb; k < ke; ++k) {
            float av = a_s[k];
            float4 b4 = *(const float4*)(B + (size_t)k * N + n0);
            acc.x = fmaf(av, b4.x, acc.x);
            acc.y = fmaf(av, b4.y, acc.y);
            acc.z = fmaf(av, b4.z, acc.z);
            acc.w = fmaf(av, b4.w, acc.w);
        }
    }
    red[kg][lane] = acc;
    __syncthreads();
    if (kg == 0 && n0 < N) {
        float4 r = red[0][lane];
        #pragma unroll
        for (int g = 1; g < 4; ++g) {
            float4 q = red[g][lane];
            r.x += q.x; r.y += q.y; r.z += q.z; r.w += q.w;
        }
        if (bias) {
            float4 bv = *(const float4*)(bias + n0);
            r.x += bv.x; r.y += bv.y; r.z += bv.z; r.w += bv.w;
        }
        if (relu) {
            r.x = fmaxf(r.x, 0.f); r.y = fmaxf(r.y, 0.f);
            r.z = fmaxf(r.z, 0.f); r.w = fmaxf(r.w, 0.f);
        }
        *(float4*)(C + (size_t)m * N + n0) = r;
    }
}

// ---------------- pooled-graph propagation: LDS-staged weights, j-split ----------------
__global__ __launch_bounds__(256) void k_pool(
    const float* __restrict__ oadj, const float* __restrict__ dinv, const float* __restrict__ h,
    const float* __restrict__ bias, float* __restrict__ outp, int F, int relu)
{
    __shared__ float wjs[KK];
    __shared__ float4 red[4][64];
    const int tid = threadIdx.x;
    const int lane = tid & 63, kg = tid >> 6;
    const int i = blockIdx.y;
    if (tid < KK)
        wjs[tid] = (oadj[tid * KK + i] + ((tid == i) ? 1.f : 0.f)) * dinv[tid];
    __syncthreads();
    const int f0 = blockIdx.x * 256 + lane * 4;
    float4 acc = make_float4(0.f, 0.f, 0.f, 0.f);
    if (f0 < F) {
        #pragma unroll 5
        for (int j = kg * 25; j < kg * 25 + 25; ++j) {
            float wv = wjs[j];
            float4 h4 = *(const float4*)(h + (size_t)j * F + f0);
            acc.x = fmaf(wv, h4.x, acc.x);
            acc.y = fmaf(wv, h4.y, acc.y);
            acc.z = fmaf(wv, h4.z, acc.z);
            acc.w = fmaf(wv, h4.w, acc.w);
        }
    }
    red[kg][lane] = acc;
    __syncthreads();
    if (kg == 0 && f0 < F) {
        float4 r = red[0][lane];
        #pragma unroll
        for (int g = 1; g < 4; ++g) {
            float4 q = red[g][lane];
            r.x += q.x; r.y += q.y; r.z += q.z; r.w += q.w;
        }
        float di = dinv[i];
        float4 bv = *(const float4*)(bias + f0);
        r.x = di * r.x + bv.x; r.y = di * r.y + bv.y;
        r.z = di * r.z + bv.z; r.w = di * r.w + bv.w;
        if (relu) {
            r.x = fmaxf(r.x, 0.f); r.y = fmaxf(r.y, 0.f);
            r.z = fmaxf(r.z, 0.f); r.w = fmaxf(r.w, 0.f);
        }
        *(float4*)(outp + (size_t)i * F + f0) = r;
    }
}

// ---------------- final dot ----------------
__global__ __launch_bounds__(256) void k_rowdot(
    const float* __restrict__ A, const float* __restrict__ wv, const float* __restrict__ b,
    float* __restrict__ outp, int K)
{
    __shared__ float red[256];
    int m = blockIdx.x, t = threadIdx.x;
    float acc = 0.f;
    for (int k = t; k < K; k += 256)
        acc = fmaf(A[(size_t)m * K + k], wv[k], acc);
    red[t] = acc;
    __syncthreads();
    for (int off = 128; off; off >>= 1) {
        if (t < off) red[t] += red[t + off];
        __syncthreads();
    }
    if (t == 0) outp[m] = red[0] + b[0];
}

extern "C" void kernel_launch(void* const* d_in, const int* in_sizes, int n_in,
                              void* d_out, int out_size, void* d_ws, size_t ws_size,
                              hipStream_t stream)
{
    const float* x   = (const float*)d_in[0];
    const int*   ei  = (const int*)  d_in[1];
    const float* ew  = (const float*)d_in[2];
    const float* w1  = (const float*)d_in[3];
    const float* b1  = (const float*)d_in[4];
    const float* w2  = (const float*)d_in[5];
    const float* b2  = (const float*)d_in[6];
    const float* aw1 = (const float*)d_in[7];
    const float* ab1 = (const float*)d_in[8];
    const float* aw2 = (const float*)d_in[9];
    const float* ab2 = (const float*)d_in[10];
    const float* w3  = (const float*)d_in[11];
    const float* b3  = (const float*)d_in[12];
    const float* w4  = (const float*)d_in[13];
    const float* b4  = (const float*)d_in[14];
    const float* pw1 = (const float*)d_in[15];
    const float* pb1 = (const float*)d_in[16];
    const float* pw2 = (const float*)d_in[17];
    const float* pb2 = (const float*)d_in[18];
    const float* pw3 = (const float*)d_in[19];
    const float* pb3 = (const float*)d_in[20];

    const int* erow = ei;
    const int* ecol = ei + EE;
    float* out = (float*)d_out;

    char* w = (char*)d_ws;
    size_t off = 0;
    auto alloc = [&](size_t bytes) -> void* {
        void* p = w + off;
        off = (off + bytes + 255) & ~(size_t)255;
        return p;
    };

    // -------- zeroed-per-call region (single memset) --------
    size_t zbeg = off;
    int*   counts   = (int*)  alloc(NN * 4);
    int*   cursor   = (int*)  alloc(NN * 4);
    int*   colcount = (int*)  alloc(KK * 4);
    int*   clcur    = (int*)  alloc(KK * 4);
    float* oadj     = (float*)alloc(KK * KK * 4);
    size_t zend = off;

    float* degsum = (float*)alloc(NN * 4);
    float* dinv   = (float*)alloc(NN * 4);
    float* dinv2  = (float*)alloc(NN * 4);
    int*   colptr = (int*)  alloc((NN + 1) * 4);
    int*   srcs   = (int*)  alloc((size_t)EE * 4);
    float* ews    = (float*)alloc((size_t)EE * 4);
    int*   colix  = (int*)  alloc((size_t)EE * 4);
    float* norms  = (float*)alloc((size_t)EE * 4);
    float* partM  = (float*)alloc((size_t)PSTR * KK * 4);
    float* partS  = (float*)alloc((size_t)PSTR * KK * 4);
    float* Lc     = (float*)alloc(KK * 4);
    int*   cass   = (int*)  alloc(NN * 4);
    int*   tie    = (int*)  alloc(NN * 4);
    int*   clptr  = (int*)  alloc((KK + 1) * 4);
    const int rowcap = NN + 2048;
    int*   rowss  = (int*)  alloc((size_t)rowcap * 4);
    float* region = (float*)alloc((size_t)KK * 256 * 4);
    float* dinvr  = (float*)alloc(KK * 4);
    float* hs1    = (float*)alloc((size_t)KK * 512 * 4);
    float* xr1    = (float*)alloc((size_t)KK * 512 * 4);
    float* hs2    = (float*)alloc((size_t)KK * 256 * 4);
    float* p1     = (float*)alloc((size_t)KK * 512 * 4);
    float* p2     = (float*)alloc((size_t)KK * 512 * 4);
    float* bufA   = (float*)alloc((size_t)NN * 256 * 4);
    float* bufB   = (float*)alloc((size_t)NN * 256 * 4);
    float* abuf   = (float*)alloc((size_t)NN * 512 * 4);
    float* zbuf   = (float*)alloc((size_t)NN * KK * 4);

    hipMemsetAsync(w + zbeg, 0, zend - zbeg, stream);

    // graph preprocessing: CSC by target, canonical (sorted) order, deterministic degsum
    k_count<<<(EE + 255) / 256, 256, 0, stream>>>(ecol, counts);
    k_scan<10><<<1, 1024, 0, stream>>>(counts, colptr, NN);
    k_scatter_e<<<(EE + 255) / 256, 256, 0, stream>>>(erow, ecol, ew, colptr, cursor,
                                                      srcs, ews, colix);
    k_sortcol<<<NN / 4, 256, 0, stream>>>(colptr, srcs, ews, degsum);
    k_dinv<<<(NN + 255) / 256, 256, 0, stream>>>(degsum, dinv, dinv2);
    k_norms<<<(EE + 255) / 256, 256, 0, stream>>>(srcs, ews, colix, dinv, norms);

    // GCN layer 1: h1 = x@w1 ; agg + self + b1 ; relu
    k_gemm<<<dim3(4, 157), 256, 0, stream>>>(x, w1, nullptr, bufA, NN, 128, 256, 0);
    k_agg<<<NN / 4, 256, 0, stream>>>(colptr, srcs, norms, bufA, dinv2, b1, bufB, 1);
    // GCN layer 2
    k_gemm<<<dim3(4, 157), 256, 0, stream>>>(bufB, w2, nullptr, bufA, NN, 256, 256, 0);
    k_agg<<<NN / 4, 256, 0, stream>>>(colptr, srcs, norms, bufA, dinv2, b2, bufB, 0);

    // assignment MLP
    k_gemm<<<dim3(8, 157), 256, 0, stream>>>(bufB, aw1, ab1, abuf, NN, 256, 512, 1);
    k_gemm<<<dim3(2, 157), 256, 0, stream>>>(abuf, aw2, ab2, zbuf, NN, 512, 100, 0);

    // softmax(axis=0) -> row argmax -> one-hot map (written straight to d_out)
    k_colpart<<<PSTR, 256, 0, stream>>>(zbuf, partM, partS);
    k_colred<<<KK, 128, 0, stream>>>(partM, partS, Lc);
    k_argmax<<<NN / 4, 256, 0, stream>>>(zbuf, Lc, out, cass, tie, colcount);

    // pooling
    k_scan<1><<<1, 128, 0, stream>>>(colcount, clptr, KK);
    k_scatter_rows<<<(NN + 255) / 256, 256, 0, stream>>>(cass, tie, out, clptr, clcur,
                                                         rowss, rowcap);
    k_region<<<KK, 256, 0, stream>>>(clptr, rowss, bufB, region);
    k_outadj<<<(EE + 255) / 256, 256, 0, stream>>>(erow, ecol, ew, cass, tie, out, oadj);
    k_finalize<<<1, 128, 0, stream>>>(oadj, colcount, dinvr, out + 1000000);

    // dense GCN 1
    k_sgemm<<<dim3(2, KK), 256, 0, stream>>>(region, w3, nullptr, hs1, 256, 512, 0);
    k_pool <<<dim3(2, KK), 256, 0, stream>>>(oadj, dinvr, hs1, b3, xr1, 512, 1);
    // dense GCN 2 -> xr (output)
    k_sgemm<<<dim3(1, KK), 256, 0, stream>>>(xr1, w4, nullptr, hs2, 512, 256, 0);
    k_pool <<<dim3(1, KK), 256, 0, stream>>>(oadj, dinvr, hs2, b4, out + 1000002, 256, 0);

    // MLP readout
    k_sgemm<<<dim3(2, KK), 256, 0, stream>>>(out + 1000002, pw1, pb1, p1, 256, 512, 1);
    k_sgemm<<<dim3(2, KK), 256, 0, stream>>>(p1, pw2, pb2, p2, 512, 512, 1);
    k_rowdot<<<KK, 256, 0, stream>>>(p2, pw3, pb3, out + 1000002 + 25600, 512);
}

// Round 15
// 462.457 us; speedup vs baseline: 1.0666x; 1.0528x over previous
//
#include <hip/hip_runtime.h>
#include <math.h>

#define NN 10000
#define EE 320000
#define KK 100
#define PSTR 625   // LSE stripes
#define RSTR 16    // rows per stripe (PSTR*RSTR == NN)

// ---------------- big fp32 GEMM: 64x64x32, register double-buffered staging ----------------
#define BM 64
#define BN 64
#define BK 32

__global__ __launch_bounds__(256) void k_gemm(
    const float* __restrict__ A, const float* __restrict__ B,
    const float* __restrict__ bias, float* __restrict__ C,
    int M, int K, int N, int relu)
{
    __shared__ float As[BK][BM + 4];
    __shared__ float Bs[BK][BN + 4];
    const int tid = threadIdx.x;
    const int bm = blockIdx.y * BM;
    const int bn = blockIdx.x * BN;
    const int tx = tid & 15, ty = tid >> 4;
    float acc[4][4] = {};
    const int ar = tid >> 3;          // 0..31
    const int ac = (tid & 7) << 2;    // 0..28
    const int br = tid >> 4;          // 0..15
    const int bc = (tid & 15) << 2;   // 0..60

    float4 ra[2], rb[2];
    #pragma unroll
    for (int p = 0; p < 2; ++p) {
        int gm = bm + ar + p * 32;
        ra[p] = make_float4(0.f, 0.f, 0.f, 0.f);
        if (gm < M) ra[p] = *(const float4*)(A + (size_t)gm * K + ac);
        int gn = bn + bc;
        rb[p] = make_float4(0.f, 0.f, 0.f, 0.f);
        if (gn < N) rb[p] = *(const float4*)(B + (size_t)(br + p * 16) * N + gn);
    }

    for (int k0 = 0; k0 < K; k0 += BK) {
        #pragma unroll
        for (int p = 0; p < 2; ++p) {
            int r = ar + p * 32;
            As[ac + 0][r] = ra[p].x;
            As[ac + 1][r] = ra[p].y;
            As[ac + 2][r] = ra[p].z;
            As[ac + 3][r] = ra[p].w;
            *(float4*)&Bs[br + p * 16][bc] = rb[p];
        }
        __syncthreads();
        int kn = k0 + BK;
        if (kn < K) {
            #pragma unroll
            for (int p = 0; p < 2; ++p) {
                int gm = bm + ar + p * 32;
                ra[p] = make_float4(0.f, 0.f, 0.f, 0.f);
                if (gm < M) ra[p] = *(const float4*)(A + (size_t)gm * K + kn + ac);
                int gn = bn + bc;
                rb[p] = make_float4(0.f, 0.f, 0.f, 0.f);
                if (gn < N) rb[p] = *(const float4*)(B + (size_t)(kn + br + p * 16) * N + gn);
            }
        }
        #pragma unroll
        for (int k = 0; k < BK; ++k) {
            float4 a4 = *(const float4*)&As[k][ty << 2];
            float4 b4 = *(const float4*)&Bs[k][tx << 2];
            float av[4] = {a4.x, a4.y, a4.z, a4.w};
            float bv[4] = {b4.x, b4.y, b4.z, b4.w};
            #pragma unroll
            for (int i = 0; i < 4; ++i)
                #pragma unroll
                for (int j = 0; j < 4; ++j)
                    acc[i][j] = fmaf(av[i], bv[j], acc[i][j]);
        }
        __syncthreads();
    }
    #pragma unroll
    for (int i = 0; i < 4; ++i) {
        int gm = bm + (ty << 2) + i;
        if (gm >= M) continue;
        #pragma unroll
        for (int j = 0; j < 4; ++j) {
            int gn = bn + (tx << 2) + j;
            if (gn >= N) continue;
            float v = acc[i][j];
            if (bias) v += bias[gn];
            if (relu) v = fmaxf(v, 0.f);
            C[(size_t)gm * N + gn] = v;
        }
    }
}

// ---------------- degree histogram (int only -> deterministic) ----------------
__global__ __launch_bounds__(256) void k_count(
    const int* __restrict__ ecol, int* __restrict__ counts)
{
    int e = blockIdx.x * 256 + threadIdx.x;
    if (e >= EE) return;
    atomicAdd(&counts[ecol[e]], 1);
}

// ---------------- single-block exclusive scan ----------------
template<int PER>
__global__ void k_scan(const int* __restrict__ cnt, int* __restrict__ ptr, int n)
{
    __shared__ int ps[1024];
    const int T = blockDim.x;
    const int t = threadIdx.x;
    int loc[PER];
    int s = 0;
    #pragma unroll
    for (int u = 0; u < PER; ++u) {
        int i = t * PER + u;
        int v = (i < n) ? cnt[i] : 0;
        loc[u] = s;
        s += v;
    }
    ps[t] = s;
    __syncthreads();
    for (int off = 1; off < T; off <<= 1) {
        int v = (t >= off) ? ps[t - off] : 0;
        __syncthreads();
        ps[t] += v;
        __syncthreads();
    }
    int base = (t > 0) ? ps[t - 1] : 0;
    #pragma unroll
    for (int u = 0; u < PER; ++u) {
        int i = t * PER + u;
        if (i < n) ptr[i] = base + loc[u];
    }
    if (t == T - 1) ptr[n] = ps[T - 1];
}

// ---------------- scatter edges (arbitrary order; canonicalized by sort after) ----------------
__global__ __launch_bounds__(256) void k_scatter_e(
    const int* __restrict__ erow, const int* __restrict__ ecol, const float* __restrict__ ew,
    const int* __restrict__ ptr, int* __restrict__ cursor,
    int* __restrict__ srcs, float* __restrict__ ews, int* __restrict__ colix)
{
    int e = blockIdx.x * 256 + threadIdx.x;
    if (e >= EE) return;
    int r = erow[e], c = ecol[e];
    int pos = ptr[c] + atomicAdd(&cursor[c], 1);
    srcs[pos] = r;
    ews[pos] = ew[e];
    colix[pos] = c;
}

// ---------------- canonical per-column sort + deterministic degsum + fused dinv ----------------
__global__ __launch_bounds__(256) void k_sortcol(
    const int* __restrict__ colptr, int* __restrict__ srcs, float* __restrict__ ews,
    float* __restrict__ degsum, float* __restrict__ dinv, float* __restrict__ dinv2)
{
    __shared__ unsigned long long keys[4][256];
    __shared__ int mxs;
    int wave = threadIdx.x >> 6, lane = threadIdx.x & 63;
    int v = blockIdx.x * 4 + wave;            // NN divisible by 4
    int beg = colptr[v];
    int cnt = colptr[v + 1] - beg;
    if (cnt > 256) cnt = 256;                 // cannot happen (Poisson(32)); safety
    if (threadIdx.x == 0) mxs = 0;
    __syncthreads();
    if (lane == 0) atomicMax(&mxs, cnt);
    for (int j = lane; j < cnt; j += 64)
        keys[wave][j] = ((unsigned long long)(unsigned)srcs[beg + j] << 32)
                      | (unsigned long long)__float_as_uint(ews[beg + j]);
    __syncthreads();
    int mx = mxs;
    for (int ph = 0; ph < mx; ++ph) {
        int r = ph & 1;
        #pragma unroll
        for (int pp = 0; pp < 2; ++pp) {
            int i = 2 * (lane + pp * 64) + r;
            if (i + 1 < cnt) {
                unsigned long long a = keys[wave][i], b = keys[wave][i + 1];
                if (a > b) { keys[wave][i] = b; keys[wave][i + 1] = a; }
            }
        }
        __syncthreads();
    }
    float s = 0.f;
    for (int j = lane; j < cnt; j += 64)
        s += __uint_as_float((unsigned)(keys[wave][j] & 0xffffffffULL));
    #pragma unroll
    for (int o = 32; o; o >>= 1) s += __shfl_xor(s, o, 64);
    if (lane == 0) {
        degsum[v] = s;
        float d = 1.0f / sqrtf(s + 1.0f);     // identical formula to old k_dinv
        dinv[v] = d;
        dinv2[v] = d * d;
    }
    for (int j = lane; j < cnt; j += 64) {
        unsigned long long k2 = keys[wave][j];
        srcs[beg + j] = (int)(k2 >> 32);
        ews[beg + j] = __uint_as_float((unsigned)(k2 & 0xffffffffULL));
    }
}

// ---------------- per-entry norm (elementwise, deterministic) ----------------
__global__ __launch_bounds__(256) void k_norms(
    const int* __restrict__ srcs, const float* __restrict__ ews, const int* __restrict__ colix,
    const float* __restrict__ dinv, float* __restrict__ norms)
{
    int p = blockIdx.x * 256 + threadIdx.x;
    if (p >= EE) return;
    norms[p] = dinv[srcs[p]] * ews[p] * dinv[colix[p]];
}

// ---------------- sparse aggregation: serial chain (bitwise-frozen order) + load prefetch ----------------
__global__ __launch_bounds__(256) void k_agg(
    const int* __restrict__ ptr, const int* __restrict__ srcs, const float* __restrict__ norms,
    const float* __restrict__ h, const float* __restrict__ dinv2, const float* __restrict__ bias,
    float* __restrict__ outp, int relu)
{
    int wave = threadIdx.x >> 6;
    int lane = threadIdx.x & 63;
    int v = blockIdx.x * 4 + wave;
    if (v >= NN) return;
    int beg = ptr[v], end = ptr[v + 1];
    const int fo = lane * 4;
    float4 acc = make_float4(0.f, 0.f, 0.f, 0.f);
    if (beg < end) {
        // software pipeline: load j+1 before FMA of j; FMA order is EXACTLY beg..end-1
        float nw = norms[beg];
        float4 hv = *(const float4*)(h + (size_t)srcs[beg] * 256 + fo);
        for (int j = beg + 1; j < end; ++j) {
            float nn = norms[j];
            float4 hn = *(const float4*)(h + (size_t)srcs[j] * 256 + fo);
            acc.x = fmaf(nw, hv.x, acc.x);
            acc.y = fmaf(nw, hv.y, acc.y);
            acc.z = fmaf(nw, hv.z, acc.z);
            acc.w = fmaf(nw, hv.w, acc.w);
            nw = nn; hv = hn;
        }
        acc.x = fmaf(nw, hv.x, acc.x);
        acc.y = fmaf(nw, hv.y, acc.y);
        acc.z = fmaf(nw, hv.z, acc.z);
        acc.w = fmaf(nw, hv.w, acc.w);
    }
    float d2 = dinv2[v];
    float4 hv2 = *(const float4*)(h + (size_t)v * 256 + fo);
    float4 bv = *(const float4*)(bias + fo);
    acc.x = fmaf(d2, hv2.x, acc.x) + bv.x;
    acc.y = fmaf(d2, hv2.y, acc.y) + bv.y;
    acc.z = fmaf(d2, hv2.z, acc.z) + bv.z;
    acc.w = fmaf(d2, hv2.w, acc.w) + bv.w;
    if (relu) {
        acc.x = fmaxf(acc.x, 0.f); acc.y = fmaxf(acc.y, 0.f);
        acc.z = fmaxf(acc.z, 0.f); acc.w = fmaxf(acc.w, 0.f);
    }
    *(float4*)(outp + (size_t)v * 256 + fo) = acc;
}

// ---------------- column LSE pass 1: 625 stripes x 16 rows, deterministic ----------------
__global__ __launch_bounds__(256) void k_colpart(
    const float* __restrict__ z, float* __restrict__ partM, float* __restrict__ partS)
{
    __shared__ float tile[RSTR][KK];
    __shared__ float m1s[128], s1s[128];
    const int p = blockIdx.x;
    const int t = threadIdx.x;
    const float4* zsrc = (const float4*)(z + (size_t)p * RSTR * KK);
    float* tf = &tile[0][0];
    for (int i = t; i < RSTR * KK / 4; i += 256)
        *(float4*)(tf + i * 4) = zsrc[i];
    __syncthreads();
    const int g = t >> 7;
    const int c = t & 127;
    float m = -INFINITY, s = 0.f;
    if (c < KK) {
        const int rb = g * 8;
        #pragma unroll
        for (int r = 0; r < 8; ++r) {
            float v = tile[rb + r][c];
            if (v <= m) {
                s += expf(v - m);
            } else {
                s = s * expf(m - v) + 1.f;
                m = v;
            }
        }
        if (g) { m1s[c] = m; s1s[c] = s; }
    }
    __syncthreads();
    if (c < KK && g == 0) {
        float m2 = m1s[c], s2 = s1s[c];
        float M = fmaxf(m, m2);
        float S = s * expf(m - M) + s2 * expf(m2 - M);
        partM[(size_t)p * KK + c] = M;
        partS[(size_t)p * KK + c] = S;
    }
}

// ---------------- column LSE pass 2: block per column, fixed-shape tree ----------------
__global__ __launch_bounds__(128) void k_colred(
    const float* __restrict__ partM, const float* __restrict__ partS, float* __restrict__ L)
{
    __shared__ float Ms[128], Ss[128];
    const int k = blockIdx.x;
    const int t = threadIdx.x;
    float m = -INFINITY, s = 0.f;
    for (int p = t; p < PSTR; p += 128) {
        float m2 = partM[(size_t)p * KK + k], s2 = partS[(size_t)p * KK + k];
        if (m2 <= m) {
            s += s2 * expf(m2 - m);
        } else {
            s = s * expf(m - m2) + s2;
            m = m2;
        }
    }
    Ms[t] = m; Ss[t] = s;
    __syncthreads();
    for (int off = 64; off; off >>= 1) {
        if (t < off) {
            float m1 = Ms[t], s1 = Ss[t];
            float m2 = Ms[t + off], s2 = Ss[t + off];
            float M = fmaxf(m1, m2);
            Ms[t] = M;
            Ss[t] = s1 * expf(m1 - M) + s2 * expf(m2 - M);
        }
        __syncthreads();
    }
    if (t == 0) L[k] = Ms[0] + logf(Ss[0]);
}

// ---------------- row argmax of (z - L): wave per row; write one-hot map ----------------
__global__ __launch_bounds__(256) void k_argmax(
    const float* __restrict__ z, const float* __restrict__ L, float* __restrict__ mapm,
    int* __restrict__ cass, int* __restrict__ tie, int* __restrict__ colcount)
{
    __shared__ float Ls[KK];
    int t = threadIdx.x;
    if (t < KK) Ls[t] = L[t];
    __syncthreads();
    int lane = t & 63, wave = t >> 6;
    int i = blockIdx.x * 4 + wave;
    if (i >= NN) return;
    const float* zr = z + (size_t)i * KK;
    float v0 = zr[lane] - Ls[lane];
    float v1 = (lane < KK - 64) ? (zr[lane + 64] - Ls[lane + 64]) : -INFINITY;
    float m = fmaxf(v0, v1);
    #pragma unroll
    for (int o = 32; o; o >>= 1) m = fmaxf(m, __shfl_xor(m, o, 64));
    bool p0 = (v0 == m);
    bool p1 = (lane < KK - 64) && (v1 == m);
    unsigned long long b0 = __ballot(p0);
    unsigned long long b1 = __ballot(p1);
    int n = __popcll(b0) + __popcll(b1);
    float* mr = mapm + (size_t)i * KK;
    mr[lane] = p0 ? 1.f : 0.f;
    if (lane < KK - 64) mr[64 + lane] = p1 ? 1.f : 0.f;
    if (p0) atomicAdd(&colcount[lane], 1);
    if (p1) atomicAdd(&colcount[64 + lane], 1);
    if (lane == 0) {
        int k0 = b0 ? (__ffsll((long long)b0) - 1) : (64 + __ffsll((long long)b1) - 1);
        cass[i] = k0;
        tie[i] = (n > 1) ? 1 : 0;
    }
}

// ---------------- scatter rows into per-cluster lists ----------------
__global__ __launch_bounds__(256) void k_scatter_rows(
    const int* __restrict__ cass, const int* __restrict__ tie, const float* __restrict__ mapm,
    const int* __restrict__ clptr, int* __restrict__ clcur, int* __restrict__ rows, int cap)
{
    int i = blockIdx.x * 256 + threadIdx.x;
    if (i >= NN) return;
    if (!tie[i]) {
        int k = cass[i];
        int pos = clptr[k] + atomicAdd(&clcur[k], 1);
        if (pos < cap) rows[pos] = i;
    } else {
        for (int k = 0; k < KK; ++k) {
            if (mapm[(size_t)i * KK + k] == 1.f) {
                int pos = clptr[k] + atomicAdd(&clcur[k], 1);
                if (pos < cap) rows[pos] = i;
            }
        }
    }
}

// ---------------- region = map^T @ hB: wave-split rows, dual accumulators ----------------
__global__ __launch_bounds__(256) void k_region(
    const int* __restrict__ clptr, const int* __restrict__ rows,
    const float* __restrict__ hB, float* __restrict__ region)
{
    __shared__ float4 red[4][64];
    const int k = blockIdx.x;
    const int lane = threadIdx.x & 63, kg = threadIdx.x >> 6;
    const int beg = clptr[k], end = clptr[k + 1];
    float4 a0 = make_float4(0.f, 0.f, 0.f, 0.f);
    float4 a1 = make_float4(0.f, 0.f, 0.f, 0.f);
    int j = beg + kg;
    for (; j + 4 < end; j += 8) {
        const float* p0 = hB + (size_t)rows[j] * 256 + lane * 4;
        const float* p1 = hB + (size_t)rows[j + 4] * 256 + lane * 4;
        float4 v0 = *(const float4*)p0;
        float4 v1 = *(const float4*)p1;
        a0.x += v0.x; a0.y += v0.y; a0.z += v0.z; a0.w += v0.w;
        a1.x += v1.x; a1.y += v1.y; a1.z += v1.z; a1.w += v1.w;
    }
    if (j < end) {
        float4 v0 = *(const float4*)(hB + (size_t)rows[j] * 256 + lane * 4);
        a0.x += v0.x; a0.y += v0.y; a0.z += v0.z; a0.w += v0.w;
    }
    a0.x += a1.x; a0.y += a1.y; a0.z += a1.z; a0.w += a1.w;
    red[kg][lane] = a0;
    __syncthreads();
    if (kg == 0) {
        float4 r = red[0][lane];
        #pragma unroll
        for (int g = 1; g < 4; ++g) {
            float4 q = red[g][lane];
            r.x += q.x; r.y += q.y; r.z += q.z; r.w += q.w;
        }
        *(float4*)(region + (size_t)k * 256 + lane * 4) = r;
    }
}

// ---------------- out_adj = map^T adj map via per-edge atomics ----------------
__global__ __launch_bounds__(256) void k_outadj(
    const int* __restrict__ erow, const int* __restrict__ ecol, const float* __restrict__ ew,
    const int* __restrict__ cass, const int* __restrict__ tie, const float* __restrict__ mapm,
    float* __restrict__ oadj)
{
    int e = blockIdx.x * 256 + threadIdx.x;
    if (e >= EE) return;
    int s = erow[e], d = ecol[e];
    float wv = ew[e];
    if (!tie[s] && !tie[d]) {
        atomicAdd(&oadj[cass[s] * KK + cass[d]], wv);
    } else {
        for (int ks = 0; ks < KK; ++ks) {
            if (mapm[(size_t)s * KK + ks] != 1.f) continue;
            for (int kd = 0; kd < KK; ++kd) {
                if (mapm[(size_t)d * KK + kd] != 1.f) continue;
                atomicAdd(&oadj[ks * KK + kd], wv);
            }
        }
    }
}

// ---------------- zero diag, colsums -> dinv_r, losses ----------------
__global__ __launch_bounds__(128) void k_finalize(
    float* __restrict__ oadj, const int* __restrict__ colcount,
    float* __restrict__ dinvr, float* __restrict__ lossout)
{
    int t = threadIdx.x;
    if (t < KK) oadj[t * KK + t] = 0.f;
    __syncthreads();
    if (t < KK) {
        float s = 1.f;   // +I on the diagonal
        for (int i = 0; i < KK; ++i) s += oadj[i * KK + t];
        dinvr[t] = 1.0f / sqrtf(s);
    }
    if (t == 0) {
        float s = 0.f;
        long long tot = 0;
        for (int k = 0; k < KK; ++k) {
            s += sqrtf((float)colcount[k] + 1e-15f);
            tot += colcount[k];
        }
        lossout[0] = -s / 1000.0f;                                  // sqrt(N*K)=1000
        lossout[1] = (float)tot * (-logf(1.0f + 1e-6f)) / 10000.0f;
    }
}

// ---------------- small GEMM: latency-optimized (tiny M, K<=512) ----------------
__global__ __launch_bounds__(256) void k_sgemm(
    const float* __restrict__ A, const float* __restrict__ B, const float* __restrict__ bias,
    float* __restrict__ C, int K, int N, int relu)
{
    __shared__ float a_s[512];
    __shared__ float4 red[4][64];
    const int tid = threadIdx.x;
    const int lane = tid & 63, kg = tid >> 6;
    const int m = blockIdx.y;
    const int n0 = blockIdx.x * 256 + lane * 4;
    for (int k = tid; k < K; k += 256) a_s[k] = A[(size_t)m * K + k];
    __syncthreads();
    float4 acc = make_float4(0.f, 0.f, 0.f, 0.f);
    const int kq = K >> 2;
    const int kb = kg * kq, ke = kb + kq;
    if (n0 < N) {
        #pragma unroll 4
        for (int k = kb; k < ke; ++k) {
            float av = a_s[k];
            float4 b4 = *(const float4*)(B + (size_t)k * N + n0);
            acc.x = fmaf(av, b4.x, acc.x);
            acc.y = fmaf(av, b4.y, acc.y);
            acc.z = fmaf(av, b4.z, acc.z);
            acc.w = fmaf(av, b4.w, acc.w);
        }
    }
    red[kg][lane] = acc;
    __syncthreads();
    if (kg == 0 && n0 < N) {
        float4 r = red[0][lane];
        #pragma unroll
        for (int g = 1; g < 4; ++g) {
            float4 q = red[g][lane];
            r.x += q.x; r.y += q.y; r.z += q.z; r.w += q.w;
        }
        if (bias) {
            float4 bv = *(const float4*)(bias + n0);
            r.x += bv.x; r.y += bv.y; r.z += bv.z; r.w += bv.w;
        }
        if (relu) {
            r.x = fmaxf(r.x, 0.f); r.y = fmaxf(r.y, 0.f);
            r.z = fmaxf(r.z, 0.f); r.w = fmaxf(r.w, 0.f);
        }
        *(float4*)(C + (size_t)m * N + n0) = r;
    }
}

// ---------------- pooled-graph propagation: LDS-staged weights, j-split ----------------
__global__ __launch_bounds__(256) void k_pool(
    const float* __restrict__ oadj, const float* __restrict__ dinv, const float* __restrict__ h,
    const float* __restrict__ bias, float* __restrict__ outp, int F, int relu)
{
    __shared__ float wjs[KK];
    __shared__ float4 red[4][64];
    const int tid = threadIdx.x;
    const int lane = tid & 63, kg = tid >> 6;
    const int i = blockIdx.y;
    if (tid < KK)
        wjs[tid] = (oadj[tid * KK + i] + ((tid == i) ? 1.f : 0.f)) * dinv[tid];
    __syncthreads();
    const int f0 = blockIdx.x * 256 + lane * 4;
    float4 acc = make_float4(0.f, 0.f, 0.f, 0.f);
    if (f0 < F) {
        #pragma unroll 5
        for (int j = kg * 25; j < kg * 25 + 25; ++j) {
            float wv = wjs[j];
            float4 h4 = *(const float4*)(h + (size_t)j * F + f0);
            acc.x = fmaf(wv, h4.x, acc.x);
            acc.y = fmaf(wv, h4.y, acc.y);
            acc.z = fmaf(wv, h4.z, acc.z);
            acc.w = fmaf(wv, h4.w, acc.w);
        }
    }
    red[kg][lane] = acc;
    __syncthreads();
    if (kg == 0 && f0 < F) {
        float4 r = red[0][lane];
        #pragma unroll
        for (int g = 1; g < 4; ++g) {
            float4 q = red[g][lane];
            r.x += q.x; r.y += q.y; r.z += q.z; r.w += q.w;
        }
        float di = dinv[i];
        float4 bv = *(const float4*)(bias + f0);
        r.x = di * r.x + bv.x; r.y = di * r.y + bv.y;
        r.z = di * r.z + bv.z; r.w = di * r.w + bv.w;
        if (relu) {
            r.x = fmaxf(r.x, 0.f); r.y = fmaxf(r.y, 0.f);
            r.z = fmaxf(r.z, 0.f); r.w = fmaxf(r.w, 0.f);
        }
        *(float4*)(outp + (size_t)i * F + f0) = r;
    }
}

// ---------------- final dot ----------------
__global__ __launch_bounds__(256) void k_rowdot(
    const float* __restrict__ A, const float* __restrict__ wv, const float* __restrict__ b,
    float* __restrict__ outp, int K)
{
    __shared__ float red[256];
    int m = blockIdx.x, t = threadIdx.x;
    float acc = 0.f;
    for (int k = t; k < K; k += 256)
        acc = fmaf(A[(size_t)m * K + k], wv[k], acc);
    red[t] = acc;
    __syncthreads();
    for (int off = 128; off; off >>= 1) {
        if (t < off) red[t] += red[t + off];
        __syncthreads();
    }
    if (t == 0) outp[m] = red[0] + b[0];
}

extern "C" void kernel_launch(void* const* d_in, const int* in_sizes, int n_in,
                              void* d_out, int out_size, void* d_ws, size_t ws_size,
                              hipStream_t stream)
{
    const float* x   = (const float*)d_in[0];
    const int*   ei  = (const int*)  d_in[1];
    const float* ew  = (const float*)d_in[2];
    const float* w1  = (const float*)d_in[3];
    const float* b1  = (const float*)d_in[4];
    const float* w2  = (const float*)d_in[5];
    const float* b2  = (const float*)d_in[6];
    const float* aw1 = (const float*)d_in[7];
    const float* ab1 = (const float*)d_in[8];
    const float* aw2 = (const float*)d_in[9];
    const float* ab2 = (const float*)d_in[10];
    const float* w3  = (const float*)d_in[11];
    const float* b3  = (const float*)d_in[12];
    const float* w4  = (const float*)d_in[13];
    const float* b4  = (const float*)d_in[14];
    const float* pw1 = (const float*)d_in[15];
    const float* pb1 = (const float*)d_in[16];
    const float* pw2 = (const float*)d_in[17];
    const float* pb2 = (const float*)d_in[18];
    const float* pw3 = (const float*)d_in[19];
    const float* pb3 = (const float*)d_in[20];

    const int* erow = ei;
    const int* ecol = ei + EE;
    float* out = (float*)d_out;

    char* w = (char*)d_ws;
    size_t off = 0;
    auto alloc = [&](size_t bytes) -> void* {
        void* p = w + off;
        off = (off + bytes + 255) & ~(size_t)255;
        return p;
    };

    // -------- zeroed-per-call region (single memset) --------
    size_t zbeg = off;
    int*   counts   = (int*)  alloc(NN * 4);
    int*   cursor   = (int*)  alloc(NN * 4);
    int*   colcount = (int*)  alloc(KK * 4);
    int*   clcur    = (int*)  alloc(KK * 4);
    float* oadj     = (float*)alloc(KK * KK * 4);
    size_t zend = off;

    float* degsum = (float*)alloc(NN * 4);
    float* dinv   = (float*)alloc(NN * 4);
    float* dinv2  = (float*)alloc(NN * 4);
    int*   colptr = (int*)  alloc((NN + 1) * 4);
    int*   srcs   = (int*)  alloc((size_t)EE * 4);
    float* ews    = (float*)alloc((size_t)EE * 4);
    int*   colix  = (int*)  alloc((size_t)EE * 4);
    float* norms  = (float*)alloc((size_t)EE * 4);
    float* partM  = (float*)alloc((size_t)PSTR * KK * 4);
    float* partS  = (float*)alloc((size_t)PSTR * KK * 4);
    float* Lc     = (float*)alloc(KK * 4);
    int*   cass   = (int*)  alloc(NN * 4);
    int*   tie    = (int*)  alloc(NN * 4);
    int*   clptr  = (int*)  alloc((KK + 1) * 4);
    const int rowcap = NN + 2048;
    int*   rowss  = (int*)  alloc((size_t)rowcap * 4);
    float* region = (float*)alloc((size_t)KK * 256 * 4);
    float* dinvr  = (float*)alloc(KK * 4);
    float* hs1    = (float*)alloc((size_t)KK * 512 * 4);
    float* xr1    = (float*)alloc((size_t)KK * 512 * 4);
    float* hs2    = (float*)alloc((size_t)KK * 256 * 4);
    float* p1     = (float*)alloc((size_t)KK * 512 * 4);
    float* p2     = (float*)alloc((size_t)KK * 512 * 4);
    float* bufA   = (float*)alloc((size_t)NN * 256 * 4);
    float* bufB   = (float*)alloc((size_t)NN * 256 * 4);
    float* abuf   = (float*)alloc((size_t)NN * 512 * 4);
    float* zbuf   = (float*)alloc((size_t)NN * KK * 4);

    hipMemsetAsync(w + zbeg, 0, zend - zbeg, stream);

    // graph preprocessing: CSC by target, canonical (sorted) order, deterministic degsum+dinv
    k_count<<<(EE + 255) / 256, 256, 0, stream>>>(ecol, counts);
    k_scan<10><<<1, 1024, 0, stream>>>(counts, colptr, NN);
    k_scatter_e<<<(EE + 255) / 256, 256, 0, stream>>>(erow, ecol, ew, colptr, cursor,
                                                      srcs, ews, colix);
    k_sortcol<<<NN / 4, 256, 0, stream>>>(colptr, srcs, ews, degsum, dinv, dinv2);
    k_norms<<<(EE + 255) / 256, 256, 0, stream>>>(srcs, ews, colix, dinv, norms);

    // GCN layer 1: h1 = x@w1 ; agg + self + b1 ; relu
    k_gemm<<<dim3(4, 157), 256, 0, stream>>>(x, w1, nullptr, bufA, NN, 128, 256, 0);
    k_agg<<<NN / 4, 256, 0, stream>>>(colptr, srcs, norms, bufA, dinv2, b1, bufB, 1);
    // GCN layer 2
    k_gemm<<<dim3(4, 157), 256, 0, stream>>>(bufB, w2, nullptr, bufA, NN, 256, 256, 0);
    k_agg<<<NN / 4, 256, 0, stream>>>(colptr, srcs, norms, bufA, dinv2, b2, bufB, 0);

    // assignment MLP
    k_gemm<<<dim3(8, 157), 256, 0, stream>>>(bufB, aw1, ab1, abuf, NN, 256, 512, 1);
    k_gemm<<<dim3(2, 157), 256, 0, stream>>>(abuf, aw2, ab2, zbuf, NN, 512, 100, 0);

    // softmax(axis=0) -> row argmax -> one-hot map (written straight to d_out)
    k_colpart<<<PSTR, 256, 0, stream>>>(zbuf, partM, partS);
    k_colred<<<KK, 128, 0, stream>>>(partM, partS, Lc);
    k_argmax<<<NN / 4, 256, 0, stream>>>(zbuf, Lc, out, cass, tie, colcount);

    // pooling
    k_scan<1><<<1, 128, 0, stream>>>(colcount, clptr, KK);
    k_scatter_rows<<<(NN + 255) / 256, 256, 0, stream>>>(cass, tie, out, clptr, clcur,
                                                         rowss, rowcap);
    k_region<<<KK, 256, 0, stream>>>(clptr, rowss, bufB, region);
    k_outadj<<<(EE + 255) / 256, 256, 0, stream>>>(erow, ecol, ew, cass, tie, out, oadj);
    k_finalize<<<1, 128, 0, stream>>>(oadj, colcount, dinvr, out + 1000000);

    // dense GCN 1
    k_sgemm<<<dim3(2, KK), 256, 0, stream>>>(region, w3, nullptr, hs1, 256, 512, 0);
    k_pool <<<dim3(2, KK), 256, 0, stream>>>(oadj, dinvr, hs1, b3, xr1, 512, 1);
    // dense GCN 2 -> xr (output)
    k_sgemm<<<dim3(1, KK), 256, 0, stream>>>(xr1, w4, nullptr, hs2, 512, 256, 0);
    k_pool <<<dim3(1, KK), 256, 0, stream>>>(oadj, dinvr, hs2, b4, out + 1000002, 256, 0);

    // MLP readout
    k_sgemm<<<dim3(2, KK), 256, 0, stream>>>(out + 1000002, pw1, pb1, p1, 256, 512, 1);
    k_sgemm<<<dim3(2, KK), 256, 0, stream>>>(p1, pw2, pb2, p2, 512, 512, 1);
    k_rowdot<<<KK, 256, 0, stream>>>(p2, pw3, pb3, out + 1000002 + 25600, 512);
}